// Round 8
// baseline (276.120 us; speedup 1.0000x reference)
//
#include <hip/hip_runtime.h>
#include <hip/hip_bf16.h>

// CrossAttention: q = x@Wq+bq; k = cond@Wk+bk; v = cond@Wv+bv
// scores = q@k^T (UNSCALED); attn = softmax(scores); out = attn@v
// B=4, Lq=Lk=4096, IN=COND=256, OUT_DIM=128. Output fp32.

typedef __attribute__((ext_vector_type(8))) short short8;
typedef __attribute__((ext_vector_type(8))) unsigned short ushort8;
typedef __attribute__((ext_vector_type(4))) unsigned short us4;
typedef __attribute__((ext_vector_type(4))) float f32x4;
typedef __attribute__((ext_vector_type(16))) float f32x16;
typedef __attribute__((ext_vector_type(4))) unsigned int u32x4;
typedef __bf16 bf16x8 __attribute__((ext_vector_type(8)));

constexpr int BATCH  = 4;
constexpr int SEQLEN = 4096;   // Lq == Lk
constexpr int DIN    = 256;
constexpr int DOUT   = 128;
constexpr int ROWS   = BATCH * SEQLEN;  // 16384

static __device__ __forceinline__ unsigned short bf16_rn(float f) {
  unsigned int u = __builtin_bit_cast(unsigned int, f);
  unsigned int r = u + 0x7FFFu + ((u >> 16) & 1u);
  return (unsigned short)(r >> 16);
}
static __device__ __forceinline__ float bf16_f32(unsigned short h) {
  return __builtin_bit_cast(float, (unsigned int)h << 16);
}

static __device__ __forceinline__ f32x4 mfma_bf16(short8 a, short8 b, f32x4 c) {
  return __builtin_amdgcn_mfma_f32_16x16x32_bf16(
      __builtin_bit_cast(bf16x8, a), __builtin_bit_cast(bf16x8, b), c, 0, 0, 0);
}
static __device__ __forceinline__ f32x16 mfma32(short8 a, short8 b, f32x16 c) {
  return __builtin_amdgcn_mfma_f32_32x32x16_bf16(
      __builtin_bit_cast(bf16x8, a), __builtin_bit_cast(bf16x8, b), c, 0, 0, 0);
}

// D = [bf16(S0) | bf16(S1)<<16]
static __device__ __forceinline__ unsigned int cvt_pk(float lo, float hi) {
  unsigned int r;
  asm("v_cvt_pk_bf16_f32 %0, %1, %2" : "=v"(r) : "v"(lo), "v"(hi));
  return r;
}
// v_permlane32_swap_b32 vdst, vsrc: a.hi32lanes <-> b.lo32lanes
static __device__ __forceinline__ void permswap(unsigned int& a, unsigned int& b) {
  asm("v_permlane32_swap_b32 %0, %1" : "+v"(a), "+v"(b));
}

static __device__ __forceinline__ int swz128(int a) {
  return a ^ (((a >> 7) & 7) << 4);
}
// K-bounce tile (row stride 256B): fold row bits 0-3 into byte bits 4-7
static __device__ __forceinline__ int swzK(int a) {
  return a ^ (((a >> 8) & 15) << 4);
}

// Fragment-major global layouts (written by proj, read coalesced by attn):
//  K: kfb[b][kblk(128)][f(8)][lane(64)] x 16B  — lane=h*32+l31 holds
//     K[kblk*32 + l31][f*16 + h*8 .. +8]           (8KB per kblk)
//  V: vfb[b][kblk(128)][dblk(4)][kk(2)][lane(64)] x 16B — lane holds
//     V[kblk*32 + kk*16 + h*8 .. +8][dblk*32 + l31] (8KB per kblk)

// ---------------- projection via MFMA, split-precision --------------------
// out = (A_hi + A_lo) @ W_bf16 + b, f32 accumulate.
// grid (ROWS/64, 3), block 256 (4 waves x 16 rows).
__global__ __launch_bounds__(256) void proj_kernel(
    const float* __restrict__ x, const float* __restrict__ cond,
    const float* __restrict__ Wq, const float* __restrict__ bq,
    const float* __restrict__ Wk, const float* __restrict__ bk,
    const float* __restrict__ Wv, const float* __restrict__ bv,
    unsigned short* __restrict__ qb, unsigned short* __restrict__ kb,
    unsigned short* __restrict__ vt)
{
  const int which = blockIdx.y;
  const float* __restrict__ src  = (which == 0) ? x  : cond;
  const float* __restrict__ W    = (which == 0) ? Wq : (which == 1 ? Wk : Wv);
  const float* __restrict__ bias = (which == 0) ? bq : (which == 1 ? bk : bv);
  const int r0 = blockIdx.x * 64;

  // LDS: Ah [64][64k] 8KB | Al 8KB | Wt [128col][64k] 16KB  (all swz128)
  __shared__ __align__(16) char lds[32768];
  char* const AhB = lds;
  char* const AlB = lds + 8192;
  char* const WtB = lds + 16384;

  const int tid  = threadIdx.x;
  const int wv   = tid >> 6;
  const int lane = tid & 63;
  const int g    = lane >> 4;
  const int c    = lane & 15;

  f32x4 acc[8];
  #pragma unroll
  for (int cf = 0; cf < 8; ++cf) acc[cf] = (f32x4){0.f, 0.f, 0.f, 0.f};

  for (int kt = 0; kt < 4; ++kt) {
    #pragma unroll
    for (int i = 0; i < 4; ++i) {
      const int idx = tid + i * 256;
      const int row = idx >> 4, f4 = idx & 15;
      const float4 a4 =
          *(const float4*)(src + (size_t)(r0 + row) * DIN + kt * 64 + f4 * 4);
      us4 hi, lo;
      const float av[4] = {a4.x, a4.y, a4.z, a4.w};
      #pragma unroll
      for (int e = 0; e < 4; ++e) {
        hi[e] = bf16_rn(av[e]);
        lo[e] = bf16_rn(av[e] - bf16_f32(hi[e]));
      }
      const int off = swz128(row * 128 + f4 * 8);
      *(us4*)(AhB + off) = hi;
      *(us4*)(AlB + off) = lo;
    }
    {
      const int col = tid & 127, half = tid >> 7;
      #pragma unroll
      for (int j = 0; j < 4; ++j) {
        const int k0 = half * 32 + j * 8;
        ushort8 wb;
        #pragma unroll
        for (int e = 0; e < 8; ++e)
          wb[e] = bf16_rn(W[(size_t)(kt * 64 + k0 + e) * DOUT + col]);
        *(ushort8*)(WtB + swz128(col * 128 + k0 * 2)) = wb;
      }
    }
    __syncthreads();

    #pragma unroll
    for (int ks = 0; ks < 2; ++ks) {
      const int aoff = (wv * 16 + c) * 128 + ks * 64 + g * 16;
      const short8 ah = *(const short8*)(AhB + swz128(aoff));
      const short8 al = *(const short8*)(AlB + swz128(aoff));
      #pragma unroll
      for (int cf = 0; cf < 8; ++cf) {
        const short8 wb =
            *(const short8*)(WtB + swz128((cf * 16 + c) * 128 + ks * 64 + g * 16));
        acc[cf] = mfma_bf16(ah, wb, acc[cf]);
        acc[cf] = mfma_bf16(al, wb, acc[cf]);
      }
    }
    __syncthreads();
  }

  if (which == 0) {
    #pragma unroll
    for (int cf = 0; cf < 8; ++cf) {
      const float bb = bias[cf * 16 + c];
      #pragma unroll
      for (int r = 0; r < 4; ++r)
        qb[(size_t)(r0 + wv * 16 + g * 4 + r) * DOUT + cf * 16 + c] =
            bf16_rn(acc[cf][r] + bb);
    }
  } else if (which == 1) {
    // K: bounce through swizzled LDS tile [64][128] bf16, then coalesced
    // fragment-major stores (1KB per wave-instruction).
    char* const Ktile = lds;   // 16KB
    #pragma unroll
    for (int cf = 0; cf < 8; ++cf) {
      const float bb = bias[cf * 16 + c];
      #pragma unroll
      for (int r = 0; r < 4; ++r) {
        const int row = wv * 16 + g * 4 + r;
        *(unsigned short*)(Ktile + swzK(row * 256 + (cf * 16 + c) * 2)) =
            bf16_rn(acc[cf][r] + bb);
      }
    }
    __syncthreads();
    const int b2     = r0 >> 12;
    const int kblkG0 = (r0 & 4095) >> 5;
    #pragma unroll
    for (int j = 0; j < 4; ++j) {
      const int i    = tid + j * 256;      // 0..1023 ushort8 units
      const int kblk = i >> 9;             // 0..1 (512 units per kblk)
      const int rem  = i & 511;
      const int f    = rem >> 6;
      const int ln   = rem & 63;
      const int row  = kblk * 32 + (ln & 31);
      const int colb = f * 32 + (ln >> 5) * 16;
      const ushort8 v = *(const ushort8*)(Ktile + swzK(row * 256 + colb));
      *(ushort8*)((char*)kb +
          (((size_t)(b2 * 128 + kblkG0 + kblk) * 8 + f) * 64 + ln) * 16) = v;
    }
  } else {
    // fragment-major V (4 consecutive keys -> one us4 store)
    const int keybase = r0 + wv * 16 + g * 4;
    const int b2   = keybase >> 12;
    const int kblk = (keybase & 4095) >> 5;
    const int kk   = (keybase >> 4) & 1;
    const int h    = (keybase >> 3) & 1;
    const int e0   = keybase & 7;          // 0 or 4
    #pragma unroll
    for (int cf = 0; cf < 8; ++cf) {
      const float bb = bias[cf * 16 + c];
      const int col  = cf * 16 + c;
      const int dblk = col >> 5, l31 = col & 31;
      us4 pk;
      #pragma unroll
      for (int r = 0; r < 4; ++r) pk[r] = bf16_rn(acc[cf][r] + bb);
      *(us4*)(vt + (((((size_t)b2 * 128 + kblk) * 4 + dblk) * 2 + kk) * 64 +
                    h * 32 + l31) * 8 + e0) = pk;
    }
  }
}

// ---------------- flash attention: register-resident, no LDS in loop ------
// Block: 1024 thr = 16 waves = 2 q-subtiles x 8 kv-splits.
// Wave: 32 q x 512 keys, KVBLK=32/iter (16 iters), 32x32x16 MFMA.
// Grid 256 -> 16 waves/CU (4/SIMD, 50% occupancy); L2 traffic halved vs QBLK=32.
constexpr int NSPLIT = 8;
constexpr int KVBLK  = 32;
constexpr int ITERS  = SEQLEN / NSPLIT / KVBLK;   // 16

__global__ __launch_bounds__(1024, 4) void attn_kernel(
    const unsigned short* __restrict__ qb,
    const unsigned short* __restrict__ kb,
    const unsigned short* __restrict__ vt,
    float* __restrict__ out)
{
  __shared__ __align__(16) float cmbPool[4][32][132];   // 67.6KB combine regions
  __shared__ float Ml[2][NSPLIT][32][2];                // 4KB

  // XCD swizzle (256 blocks = 8 XCD x 32): one batch per XCD-pair -> L2-fit
  const int bid = ((blockIdx.x & 7) << 5) | (blockIdx.x >> 3);
  const int qt  = bid & 63;    // 64 q-tiles (of 64 queries) per batch
  const int b   = bid >> 6;
  const int tid = threadIdx.x;
  const int wid   = tid >> 6;
  const int qsub  = wid & 1;
  const int split = wid >> 1;  // 0..7
  const int lane  = tid & 63;
  const int ql = lane & 31;    // query column this lane owns
  const int h  = lane >> 5;    // half-wave

  const int q0 = qt * 64 + qsub * 32;

  // ---- Q B-fragments (once): lane holds Q[q0+ql][f*16 + h*8 .. +8] ----
  short8 qf[8];
  {
    const char* qp = (const char*)(qb + (size_t)(b * SEQLEN + q0 + ql) * DOUT) + h * 16;
    #pragma unroll
    for (int f = 0; f < 8; ++f) qf[f] = *(const short8*)(qp + f * 32);
  }

  // ---- fragment-major streaming bases (coalesced: lane*16 contiguous) ----
  const int kblk0 = split * (SEQLEN / NSPLIT / 32);   // split*16
  const char* kfb = (const char*)kb + ((size_t)b * 128 + kblk0) * 8192 + lane * 16;
  const char* vfb = (const char*)vt + ((size_t)b * 128 + kblk0) * 8192 + lane * 16;

  f32x16 acc[4];
  #pragma unroll
  for (int d = 0; d < 4; ++d)
    #pragma unroll
    for (int r = 0; r < 16; ++r) acc[d][r] = 0.f;
  float mc = -1e30f, lc = 0.f;

  // preload t=0
  short8 kf[8], vf[4][2];
  #pragma unroll
  for (int f = 0; f < 8; ++f) kf[f] = *(const short8*)(kfb + f * 1024);
  #pragma unroll
  for (int d = 0; d < 4; ++d)
    #pragma unroll
    for (int kk = 0; kk < 2; ++kk)
      vf[d][kk] = *(const short8*)(vfb + (d * 2 + kk) * 1024);

  for (int t = 0; t < ITERS; ++t) {
    const bool more = (t + 1 < ITERS);

    // ---- S^T = K Q^T : lane holds S[16 keys][query ql] ----
    f32x16 s;
    #pragma unroll
    for (int r = 0; r < 16; ++r) s[r] = 0.f;
    __builtin_amdgcn_s_setprio(1);
    #pragma unroll
    for (int f = 0; f < 8; ++f) s = mfma32(kf[f], qf[f], s);
    __builtin_amdgcn_s_setprio(0);

    // prefetch K(t+1)  (contiguous 8KB block)
    if (more) {
      kfb += 8192;
      #pragma unroll
      for (int f = 0; f < 8; ++f) kf[f] = *(const short8*)(kfb + f * 1024);
    }

    // ---- softmax, defer-max (T13) ----
    float tm = s[0];
    #pragma unroll
    for (int r = 1; r < 16; ++r) tm = fmaxf(tm, s[r]);
    if (!__all(tm <= mc + 8.f)) {
      float tr = fmaxf(tm, __shfl_xor(tm, 32));
      const float mnew  = fmaxf(mc, tr);
      const float sc    = __expf(mc - mnew);
      mc = mnew;
      lc *= sc;
      #pragma unroll
      for (int d = 0; d < 4; ++d)
        #pragma unroll
        for (int r = 0; r < 16; ++r) acc[d][r] *= sc;
    }
    float p[16];
    float rs = 0.f;
    #pragma unroll
    for (int r = 0; r < 16; ++r) {
      p[r] = __expf(s[r] - mc);
      rs += p[r];
    }
    lc += rs;

    // ---- P -> B-fragments in-register (T12) ----
    short8 pfrag[2];
    #pragma unroll
    for (int kk = 0; kk < 2; ++kk) {
      unsigned int A  = cvt_pk(p[kk * 8 + 0], p[kk * 8 + 1]);
      unsigned int Bv = cvt_pk(p[kk * 8 + 2], p[kk * 8 + 3]);
      unsigned int C  = cvt_pk(p[kk * 8 + 4], p[kk * 8 + 5]);
      unsigned int Dv = cvt_pk(p[kk * 8 + 6], p[kk * 8 + 7]);
      permswap(A, C);    // A = word0, C = word2
      permswap(Bv, Dv);  // Bv = word1, Dv = word3
      const u32x4 w = {A, Bv, C, Dv};
      pfrag[kk] = __builtin_bit_cast(short8, w);
    }

    // ---- O^T += V^T P^T ----
    __builtin_amdgcn_s_setprio(1);
    #pragma unroll
    for (int d = 0; d < 4; ++d)
      #pragma unroll
      for (int kk = 0; kk < 2; ++kk)
        acc[d] = mfma32(vf[d][kk], pfrag[kk], acc[d]);
    __builtin_amdgcn_s_setprio(0);

    // prefetch V(t+1)  (contiguous 8KB block)
    if (more) {
      vfb += 8192;
      #pragma unroll
      for (int d = 0; d < 4; ++d)
        #pragma unroll
        for (int kk = 0; kk < 2; ++kk)
          vf[d][kk] = *(const short8*)(vfb + (d * 2 + kk) * 1024);
    }
  }

  // ---- cross-split combine (8 partials per qsub; tree, qsub serialized) ----
  lc += __shfl_xor(lc, 32);    // fold key-halves (same query)
  if (lane < 32) { Ml[qsub][split][ql][0] = mc; Ml[qsub][split][ql][1] = lc; }
  __syncthreads();

  float mg = -1e30f, lsum = 0.f;
  #pragma unroll
  for (int s2 = 0; s2 < NSPLIT; ++s2) mg = fmaxf(mg, Ml[qsub][s2][ql][0]);
  #pragma unroll
  for (int s2 = 0; s2 < NSPLIT; ++s2)
    lsum += Ml[qsub][s2][ql][1] * __expf(Ml[qsub][s2][ql][0] - mg);
  const float fac = __expf(mc - mg);
  #pragma unroll
  for (int d = 0; d < 4; ++d)
    #pragma unroll
    for (int r = 0; r < 16; ++r) acc[d][r] *= fac;

  auto writeReg = [&](float* reg) {
    #pragma unroll
    for (int d = 0; d < 4; ++d)
      #pragma unroll
      for (int rr = 0; rr < 4; ++rr) {
        const f32x4 v = {acc[d][rr*4+0], acc[d][rr*4+1], acc[d][rr*4+2], acc[d][rr*4+3]};
        *(f32x4*)(reg + ql * 132 + d * 32 + rr * 8 + h * 4) = v;
      }
  };
  auto addReg = [&](const float* reg) {
    #pragma unroll
    for (int d = 0; d < 4; ++d)
      #pragma unroll
      for (int rr = 0; rr < 4; ++rr) {
        const f32x4 v = *(const f32x4*)(reg + ql * 132 + d * 32 + rr * 8 + h * 4);
        acc[d][rr*4+0] += v.x; acc[d][rr*4+1] += v.y;
        acc[d][rr*4+2] += v.z; acc[d][rr*4+3] += v.w;
      }
  };

  #pragma unroll
  for (int qs = 0; qs < 2; ++qs) {
    const bool me = (qsub == qs);
    if (me && split >= 4) writeReg(&cmbPool[split - 4][0][0]);
    __syncthreads();
    if (me && split < 4) addReg(&cmbPool[split][0][0]);
    __syncthreads();
    if (me && (split == 2 || split == 3)) writeReg(&cmbPool[split - 2][0][0]);
    __syncthreads();
    if (me && split < 2) addReg(&cmbPool[split][0][0]);
    __syncthreads();
    if (me && split == 1) writeReg(&cmbPool[0][0][0]);
    __syncthreads();
    if (me && split == 0) {
      addReg(&cmbPool[0][0][0]);
      const float inv = 1.f / lsum;
      float* const op = out + (size_t)(b * SEQLEN + q0 + ql) * DOUT;
      #pragma unroll
      for (int d = 0; d < 4; ++d)
        #pragma unroll
        for (int rr = 0; rr < 4; ++rr) {
          f32x4 o;
          o.x = acc[d][rr*4+0] * inv;
          o.y = acc[d][rr*4+1] * inv;
          o.z = acc[d][rr*4+2] * inv;
          o.w = acc[d][rr*4+3] * inv;
          *(f32x4*)(op + d * 32 + rr * 8 + h * 4) = o;
        }
    }
    if (qs == 0) __syncthreads();   // protect regions before qsub-1 reuse
  }
}

extern "C" void kernel_launch(void* const* d_in, const int* in_sizes, int n_in,
                              void* d_out, int out_size, void* d_ws, size_t ws_size,
                              hipStream_t stream) {
  const float* x    = (const float*)d_in[0];
  const float* cond = (const float*)d_in[1];
  const float* Wq   = (const float*)d_in[2];
  const float* bq   = (const float*)d_in[3];
  const float* Wk   = (const float*)d_in[4];
  const float* bk   = (const float*)d_in[5];
  const float* Wv   = (const float*)d_in[6];
  const float* bv   = (const float*)d_in[7];
  float* out = (float*)d_out;

  unsigned short* qb = (unsigned short*)d_ws;                 // 4MB row-major
  unsigned short* kb = qb + (size_t)ROWS * DOUT;              // 4MB fragment-major
  unsigned short* vt = kb + (size_t)ROWS * DOUT;              // 4MB fragment-major

  proj_kernel<<<dim3(ROWS / 64, 3), 256, 0, stream>>>(
      x, cond, Wq, bq, Wk, bk, Wv, bv, qb, kb, vt);

  attn_kernel<<<dim3(BATCH * (SEQLEN / 64)), 1024, 0, stream>>>(
      qb, kb, vt, out);
}

// Round 9
// 74.571 us; speedup vs baseline: 3.7028x; 3.7028x over previous
//
#include <hip/hip_runtime.h>
#include <hip/hip_bf16.h>

// CrossAttention: q = x@Wq+bq; k = cond@Wk+bk; v = cond@Wv+bv
// scores = q@k^T (UNSCALED); attn = softmax(scores); out = attn@v
// B=4, Lq=Lk=4096, IN=COND=256, OUT_DIM=128. Output fp32.
//
// q is stored pre-scaled by log2(e) (applied in f32 before the bf16 round),
// so softmax runs in the exp2 domain: one native v_exp_f32 per score.

typedef __attribute__((ext_vector_type(8))) short short8;
typedef __attribute__((ext_vector_type(8))) unsigned short ushort8;
typedef __attribute__((ext_vector_type(4))) unsigned short us4;
typedef __attribute__((ext_vector_type(4))) float f32x4;
typedef __attribute__((ext_vector_type(16))) float f32x16;
typedef __attribute__((ext_vector_type(4))) unsigned int u32x4;
typedef __bf16 bf16x8 __attribute__((ext_vector_type(8)));

constexpr int BATCH  = 4;
constexpr int SEQLEN = 4096;   // Lq == Lk
constexpr int DIN    = 256;
constexpr int DOUT   = 128;
constexpr int ROWS   = BATCH * SEQLEN;  // 16384
constexpr float LOG2E = 1.4426950408889634f;

static __device__ __forceinline__ unsigned short bf16_rn(float f) {
  unsigned int u = __builtin_bit_cast(unsigned int, f);
  unsigned int r = u + 0x7FFFu + ((u >> 16) & 1u);
  return (unsigned short)(r >> 16);
}
static __device__ __forceinline__ float bf16_f32(unsigned short h) {
  return __builtin_bit_cast(float, (unsigned int)h << 16);
}

static __device__ __forceinline__ f32x4 mfma_bf16(short8 a, short8 b, f32x4 c) {
  return __builtin_amdgcn_mfma_f32_16x16x32_bf16(
      __builtin_bit_cast(bf16x8, a), __builtin_bit_cast(bf16x8, b), c, 0, 0, 0);
}
static __device__ __forceinline__ f32x16 mfma32(short8 a, short8 b, f32x16 c) {
  return __builtin_amdgcn_mfma_f32_32x32x16_bf16(
      __builtin_bit_cast(bf16x8, a), __builtin_bit_cast(bf16x8, b), c, 0, 0, 0);
}

// D = [bf16(S0) | bf16(S1)<<16]
static __device__ __forceinline__ unsigned int cvt_pk(float lo, float hi) {
  unsigned int r;
  asm("v_cvt_pk_bf16_f32 %0, %1, %2" : "=v"(r) : "v"(lo), "v"(hi));
  return r;
}
// v_permlane32_swap_b32 vdst, vsrc: a.hi32lanes <-> b.lo32lanes
static __device__ __forceinline__ void permswap(unsigned int& a, unsigned int& b) {
  asm("v_permlane32_swap_b32 %0, %1" : "+v"(a), "+v"(b));
}

static __device__ __forceinline__ int swz128(int a) {
  return a ^ (((a >> 7) & 7) << 4);
}
// K-bounce tile (row stride 256B): fold row bits 0-3 into byte bits 4-7
static __device__ __forceinline__ int swzK(int a) {
  return a ^ (((a >> 8) & 15) << 4);
}

// Fragment-major global layouts (written by proj, read coalesced by attn):
//  K: kfb[b][kblk(128)][f(8)][lane(64)] x 16B  — lane=h*32+l31 holds
//     K[kblk*32 + l31][f*16 + h*8 .. +8]           (8KB per kblk)
//  V: vfb[b][kblk(128)][dblk(4)][kk(2)][lane(64)] x 16B — lane holds
//     V[kblk*32 + kk*16 + h*8 .. +8][dblk*32 + l31] (8KB per kblk)

// ---------------- projection via MFMA, split-precision --------------------
__global__ __launch_bounds__(256) void proj_kernel(
    const float* __restrict__ x, const float* __restrict__ cond,
    const float* __restrict__ Wq, const float* __restrict__ bq,
    const float* __restrict__ Wk, const float* __restrict__ bk,
    const float* __restrict__ Wv, const float* __restrict__ bv,
    unsigned short* __restrict__ qb, unsigned short* __restrict__ kb,
    unsigned short* __restrict__ vt)
{
  const int which = blockIdx.y;
  const float* __restrict__ src  = (which == 0) ? x  : cond;
  const float* __restrict__ W    = (which == 0) ? Wq : (which == 1 ? Wk : Wv);
  const float* __restrict__ bias = (which == 0) ? bq : (which == 1 ? bk : bv);
  const int r0 = blockIdx.x * 64;

  __shared__ __align__(16) char lds[32768];
  char* const AhB = lds;
  char* const AlB = lds + 8192;
  char* const WtB = lds + 16384;

  const int tid  = threadIdx.x;
  const int wv   = tid >> 6;
  const int lane = tid & 63;
  const int g    = lane >> 4;
  const int c    = lane & 15;

  f32x4 acc[8];
  #pragma unroll
  for (int cf = 0; cf < 8; ++cf) acc[cf] = (f32x4){0.f, 0.f, 0.f, 0.f};

  for (int kt = 0; kt < 4; ++kt) {
    #pragma unroll
    for (int i = 0; i < 4; ++i) {
      const int idx = tid + i * 256;
      const int row = idx >> 4, f4 = idx & 15;
      const float4 a4 =
          *(const float4*)(src + (size_t)(r0 + row) * DIN + kt * 64 + f4 * 4);
      us4 hi, lo;
      const float av[4] = {a4.x, a4.y, a4.z, a4.w};
      #pragma unroll
      for (int e = 0; e < 4; ++e) {
        hi[e] = bf16_rn(av[e]);
        lo[e] = bf16_rn(av[e] - bf16_f32(hi[e]));
      }
      const int off = swz128(row * 128 + f4 * 8);
      *(us4*)(AhB + off) = hi;
      *(us4*)(AlB + off) = lo;
    }
    {
      const int col = tid & 127, half = tid >> 7;
      #pragma unroll
      for (int j = 0; j < 4; ++j) {
        const int k0 = half * 32 + j * 8;
        ushort8 wb;
        #pragma unroll
        for (int e = 0; e < 8; ++e)
          wb[e] = bf16_rn(W[(size_t)(kt * 64 + k0 + e) * DOUT + col]);
        *(ushort8*)(WtB + swz128(col * 128 + k0 * 2)) = wb;
      }
    }
    __syncthreads();

    #pragma unroll
    for (int ks = 0; ks < 2; ++ks) {
      const int aoff = (wv * 16 + c) * 128 + ks * 64 + g * 16;
      const short8 ah = *(const short8*)(AhB + swz128(aoff));
      const short8 al = *(const short8*)(AlB + swz128(aoff));
      #pragma unroll
      for (int cf = 0; cf < 8; ++cf) {
        const short8 wb =
            *(const short8*)(WtB + swz128((cf * 16 + c) * 128 + ks * 64 + g * 16));
        acc[cf] = mfma_bf16(ah, wb, acc[cf]);
        acc[cf] = mfma_bf16(al, wb, acc[cf]);
      }
    }
    __syncthreads();
  }

  if (which == 0) {
    // q scaled by log2(e) in f32 BEFORE the bf16 round (exp2-domain softmax)
    #pragma unroll
    for (int cf = 0; cf < 8; ++cf) {
      const float bb = bias[cf * 16 + c];
      #pragma unroll
      for (int r = 0; r < 4; ++r)
        qb[(size_t)(r0 + wv * 16 + g * 4 + r) * DOUT + cf * 16 + c] =
            bf16_rn((acc[cf][r] + bb) * LOG2E);
    }
  } else if (which == 1) {
    // K: bounce through swizzled LDS tile [64][128] bf16, then coalesced
    // fragment-major stores (1KB per wave-instruction).
    char* const Ktile = lds;   // 16KB
    #pragma unroll
    for (int cf = 0; cf < 8; ++cf) {
      const float bb = bias[cf * 16 + c];
      #pragma unroll
      for (int r = 0; r < 4; ++r) {
        const int row = wv * 16 + g * 4 + r;
        *(unsigned short*)(Ktile + swzK(row * 256 + (cf * 16 + c) * 2)) =
            bf16_rn(acc[cf][r] + bb);
      }
    }
    __syncthreads();
    const int b2     = r0 >> 12;
    const int kblkG0 = (r0 & 4095) >> 5;
    #pragma unroll
    for (int j = 0; j < 4; ++j) {
      const int i    = tid + j * 256;      // 0..1023 ushort8 units
      const int kblk = i >> 9;
      const int rem  = i & 511;
      const int f    = rem >> 6;
      const int ln   = rem & 63;
      const int row  = kblk * 32 + (ln & 31);
      const int colb = f * 32 + (ln >> 5) * 16;
      const ushort8 v = *(const ushort8*)(Ktile + swzK(row * 256 + colb));
      *(ushort8*)((char*)kb +
          (((size_t)(b2 * 128 + kblkG0 + kblk) * 8 + f) * 64 + ln) * 16) = v;
    }
  } else {
    // fragment-major V (4 consecutive keys -> one us4 store)
    const int keybase = r0 + wv * 16 + g * 4;
    const int b2   = keybase >> 12;
    const int kblk = (keybase & 4095) >> 5;
    const int kk   = (keybase >> 4) & 1;
    const int h    = (keybase >> 3) & 1;
    const int e0   = keybase & 7;
    #pragma unroll
    for (int cf = 0; cf < 8; ++cf) {
      const float bb = bias[cf * 16 + c];
      const int col  = cf * 16 + c;
      const int dblk = col >> 5, l31 = col & 31;
      us4 pk;
      #pragma unroll
      for (int r = 0; r < 4; ++r) pk[r] = bf16_rn(acc[cf][r] + bb);
      *(us4*)(vt + (((((size_t)b2 * 128 + kblk) * 4 + dblk) * 2 + kk) * 64 +
                    h * 32 + l31) * 8 + e0) = pk;
    }
  }
}

// ---------------- flash attention: register-resident, no LDS in loop ------
// Block: 256 thr = 4 waves = 4 kv-splits of one 32-query tile.
// Wave: 32 q x 1024 keys, KVBLK=32/iter (32 iters), 32x32x16 MFMA.
// 2 waves/SIMD (register-resident design; launch_bounds(256,2) verified r7).
// exp2-domain softmax (q pre-scaled); defer-max T13; in-register P (T12).
constexpr int NSPLIT = 4;
constexpr int QBLK   = 32;
constexpr int KVBLK  = 32;
constexpr int ITERS  = SEQLEN / NSPLIT / KVBLK;   // 32

__global__ __launch_bounds__(256, 2) void attn_kernel(
    const unsigned short* __restrict__ qb,
    const unsigned short* __restrict__ kb,
    const unsigned short* __restrict__ vt,
    float* __restrict__ out)
{
  __shared__ __align__(16) float cmb[2][32][132];   // 33.8KB combine buffer
  __shared__ float Ml[NSPLIT][32][2];               // 1KB

  // XCD swizzle (512 blocks = 8 XCD x 64): one batch per XCD-pair -> L2-fit
  const int bid = ((blockIdx.x & 7) << 6) | (blockIdx.x >> 3);
  const int qt  = bid & 127;
  const int b   = bid >> 7;
  const int tid = threadIdx.x;
  const int split = tid >> 6;
  const int lane  = tid & 63;
  const int ql = lane & 31;   // query column this lane owns
  const int h  = lane >> 5;   // half-wave

  const int q0 = qt * QBLK;

  // ---- Q B-fragments (once): lane holds Q[q0+ql][f*16 + h*8 .. +8] ----
  short8 qf[8];
  {
    const char* qp = (const char*)(qb + (size_t)(b * SEQLEN + q0 + ql) * DOUT) + h * 16;
    #pragma unroll
    for (int f = 0; f < 8; ++f) qf[f] = *(const short8*)(qp + f * 32);
  }

  // ---- fragment-major streaming bases (coalesced: lane*16 contiguous) ----
  const int kblk0 = split * (SEQLEN / NSPLIT / 32);   // split*32
  const char* kfb = (const char*)kb + ((size_t)b * 128 + kblk0) * 8192 + lane * 16;
  const char* vfb = (const char*)vt + ((size_t)b * 128 + kblk0) * 8192 + lane * 16;

  f32x16 acc[4];
  #pragma unroll
  for (int d = 0; d < 4; ++d)
    #pragma unroll
    for (int r = 0; r < 16; ++r) acc[d][r] = 0.f;
  float mc = -1e30f, lc = 0.f;

  // preload t=0
  short8 kf[8], vf[4][2];
  #pragma unroll
  for (int f = 0; f < 8; ++f) kf[f] = *(const short8*)(kfb + f * 1024);
  #pragma unroll
  for (int d = 0; d < 4; ++d)
    #pragma unroll
    for (int kk = 0; kk < 2; ++kk)
      vf[d][kk] = *(const short8*)(vfb + (d * 2 + kk) * 1024);

  for (int t = 0; t < ITERS; ++t) {
    const bool more = (t + 1 < ITERS);

    // ---- S^T = K Q^T : lane holds S[16 keys][query ql], log2 domain ----
    f32x16 s;
    #pragma unroll
    for (int r = 0; r < 16; ++r) s[r] = 0.f;
    __builtin_amdgcn_s_setprio(1);
    #pragma unroll
    for (int f = 0; f < 8; ++f) s = mfma32(kf[f], qf[f], s);
    __builtin_amdgcn_s_setprio(0);

    // prefetch K(t+1)  (contiguous 8KB block)
    if (more) {
      kfb += 8192;
      #pragma unroll
      for (int f = 0; f < 8; ++f) kf[f] = *(const short8*)(kfb + f * 1024);
    }

    // ---- softmax, defer-max (T13), exp2 domain ----
    // tile max as a fused tree (v_max3-friendly), depth 3
    float m01 = fmaxf(fmaxf(s[0],  s[1]),  s[2]);
    float m02 = fmaxf(fmaxf(s[3],  s[4]),  s[5]);
    float m03 = fmaxf(fmaxf(s[6],  s[7]),  s[8]);
    float m04 = fmaxf(fmaxf(s[9],  s[10]), s[11]);
    float m05 = fmaxf(fmaxf(s[12], s[13]), s[14]);
    float m11 = fmaxf(fmaxf(m01, m02), m03);
    float m12 = fmaxf(fmaxf(m04, m05), s[15]);
    float tm  = fmaxf(m11, m12);
    if (!__all(tm <= mc + 8.f)) {      // 8 in log2 units: P <= 256
      float tr = fmaxf(tm, __shfl_xor(tm, 32));
      const float mnew  = fmaxf(mc, tr);
      const float sc    = exp2f(mc - mnew);
      mc = mnew;
      lc *= sc;
      #pragma unroll
      for (int d = 0; d < 4; ++d)
        #pragma unroll
        for (int r = 0; r < 16; ++r) acc[d][r] *= sc;
    }
    float p[16];
    float rs = 0.f;
    #pragma unroll
    for (int r = 0; r < 16; ++r) {
      p[r] = exp2f(s[r] - mc);         // native v_exp_f32
      rs += p[r];
    }
    lc += rs;

    // ---- P -> B-fragments in-register (T12) ----
    short8 pfrag[2];
    #pragma unroll
    for (int kk = 0; kk < 2; ++kk) {
      unsigned int A  = cvt_pk(p[kk * 8 + 0], p[kk * 8 + 1]);
      unsigned int Bv = cvt_pk(p[kk * 8 + 2], p[kk * 8 + 3]);
      unsigned int C  = cvt_pk(p[kk * 8 + 4], p[kk * 8 + 5]);
      unsigned int Dv = cvt_pk(p[kk * 8 + 6], p[kk * 8 + 7]);
      permswap(A, C);    // A = word0, C = word2
      permswap(Bv, Dv);  // Bv = word1, Dv = word3
      const u32x4 w = {A, Bv, C, Dv};
      pfrag[kk] = __builtin_bit_cast(short8, w);
    }

    // ---- O^T += V^T P^T ----
    __builtin_amdgcn_s_setprio(1);
    #pragma unroll
    for (int d = 0; d < 4; ++d)
      #pragma unroll
      for (int kk = 0; kk < 2; ++kk)
        acc[d] = mfma32(vf[d][kk], pfrag[kk], acc[d]);
    __builtin_amdgcn_s_setprio(0);

    // prefetch V(t+1)  (contiguous 8KB block)
    if (more) {
      vfb += 8192;
      #pragma unroll
      for (int d = 0; d < 4; ++d)
        #pragma unroll
        for (int kk = 0; kk < 2; ++kk)
          vf[d][kk] = *(const short8*)(vfb + (d * 2 + kk) * 1024);
    }
  }

  // ---- cross-split combine (exp2 domain) ----
  lc += __shfl_xor(lc, 32);    // fold key-halves (same query)
  if (lane < 32) { Ml[split][ql][0] = mc; Ml[split][ql][1] = lc; }
  __syncthreads();

  float mg = -1e30f, lsum = 0.f;
  #pragma unroll
  for (int s2 = 0; s2 < NSPLIT; ++s2) mg = fmaxf(mg, Ml[s2][ql][0]);
  #pragma unroll
  for (int s2 = 0; s2 < NSPLIT; ++s2)
    lsum += Ml[s2][ql][1] * exp2f(Ml[s2][ql][0] - mg);
  const float fac = exp2f(mc - mg);
  #pragma unroll
  for (int d = 0; d < 4; ++d)
    #pragma unroll
    for (int r = 0; r < 16; ++r) acc[d][r] *= fac;

  // tree: {1,3} write -> {0,2} add -> {2} writes -> {0} adds -> out
  if (split & 1) {
    float* reg = &cmb[split >> 1][0][0];
    #pragma unroll
    for (int d = 0; d < 4; ++d)
      #pragma unroll
      for (int rr = 0; rr < 4; ++rr) {
        const f32x4 v = {acc[d][rr*4+0], acc[d][rr*4+1], acc[d][rr*4+2], acc[d][rr*4+3]};
        *(f32x4*)(reg + ql * 132 + d * 32 + rr * 8 + h * 4) = v;
      }
  }
  __syncthreads();
  if (!(split & 1)) {
    const float* reg = &cmb[split >> 1][0][0];
    #pragma unroll
    for (int d = 0; d < 4; ++d)
      #pragma unroll
      for (int rr = 0; rr < 4; ++rr) {
        const f32x4 v = *(const f32x4*)(reg + ql * 132 + d * 32 + rr * 8 + h * 4);
        acc[d][rr*4+0] += v.x; acc[d][rr*4+1] += v.y;
        acc[d][rr*4+2] += v.z; acc[d][rr*4+3] += v.w;
      }
  }
  __syncthreads();
  if (split == 2) {
    float* reg = &cmb[0][0][0];
    #pragma unroll
    for (int d = 0; d < 4; ++d)
      #pragma unroll
      for (int rr = 0; rr < 4; ++rr) {
        const f32x4 v = {acc[d][rr*4+0], acc[d][rr*4+1], acc[d][rr*4+2], acc[d][rr*4+3]};
        *(f32x4*)(reg + ql * 132 + d * 32 + rr * 8 + h * 4) = v;
      }
  }
  __syncthreads();
  if (split == 0) {
    const float* reg = &cmb[0][0][0];
    const float inv = 1.f / lsum;
    float* const op = out + (size_t)(b * SEQLEN + q0 + ql) * DOUT;
    #pragma unroll
    for (int d = 0; d < 4; ++d)
      #pragma unroll
      for (int rr = 0; rr < 4; ++rr) {
        const f32x4 v = *(const f32x4*)(reg + ql * 132 + d * 32 + rr * 8 + h * 4);
        f32x4 o;
        o.x = (acc[d][rr*4+0] + v.x) * inv;
        o.y = (acc[d][rr*4+1] + v.y) * inv;
        o.z = (acc[d][rr*4+2] + v.z) * inv;
        o.w = (acc[d][rr*4+3] + v.w) * inv;
        *(f32x4*)(op + d * 32 + rr * 8 + h * 4) = o;
      }
  }
}

extern "C" void kernel_launch(void* const* d_in, const int* in_sizes, int n_in,
                              void* d_out, int out_size, void* d_ws, size_t ws_size,
                              hipStream_t stream) {
  const float* x    = (const float*)d_in[0];
  const float* cond = (const float*)d_in[1];
  const float* Wq   = (const float*)d_in[2];
  const float* bq   = (const float*)d_in[3];
  const float* Wk   = (const float*)d_in[4];
  const float* bk   = (const float*)d_in[5];
  const float* Wv   = (const float*)d_in[6];
  const float* bv   = (const float*)d_in[7];
  float* out = (float*)d_out;

  unsigned short* qb = (unsigned short*)d_ws;                 // 4MB row-major (log2e-scaled)
  unsigned short* kb = qb + (size_t)ROWS * DOUT;              // 4MB fragment-major
  unsigned short* vt = kb + (size_t)ROWS * DOUT;              // 4MB fragment-major

  proj_kernel<<<dim3(ROWS / 64, 3), 256, 0, stream>>>(
      x, cond, Wq, bq, Wk, bk, Wv, bv, qb, kb, vt);

  attn_kernel<<<dim3(BATCH * (SEQLEN / QBLK)), 256, 0, stream>>>(
      qb, kb, vt, out);
}

// Round 10
// 71.443 us; speedup vs baseline: 3.8649x; 1.0438x over previous
//
#include <hip/hip_runtime.h>
#include <hip/hip_bf16.h>

// CrossAttention: q = x@Wq+bq; k = cond@Wk+bk; v = cond@Wv+bv
// scores = q@k^T (UNSCALED); attn = softmax(scores); out = attn@v
// B=4, Lq=Lk=4096, IN=COND=256, OUT_DIM=128. Output fp32.
//
// q stored pre-scaled by log2(e); softmax in exp2 domain via NATIVE v_exp_f32
// (__builtin_amdgcn_exp2f). r9 lesson: plain exp2f -> __ocml_exp2_f32 precise
// path (~20 VALU ops); __expf was 2; native exp2 is 1.

typedef __attribute__((ext_vector_type(8))) short short8;
typedef __attribute__((ext_vector_type(8))) unsigned short ushort8;
typedef __attribute__((ext_vector_type(4))) unsigned short us4;
typedef __attribute__((ext_vector_type(4))) float f32x4;
typedef __attribute__((ext_vector_type(16))) float f32x16;
typedef __attribute__((ext_vector_type(4))) unsigned int u32x4;
typedef __bf16 bf16x8 __attribute__((ext_vector_type(8)));

constexpr int BATCH  = 4;
constexpr int SEQLEN = 4096;   // Lq == Lk
constexpr int DIN    = 256;
constexpr int DOUT   = 128;
constexpr int ROWS   = BATCH * SEQLEN;  // 16384
constexpr float LOG2E = 1.4426950408889634f;

static __device__ __forceinline__ unsigned short bf16_rn(float f) {
  unsigned int u = __builtin_bit_cast(unsigned int, f);
  unsigned int r = u + 0x7FFFu + ((u >> 16) & 1u);
  return (unsigned short)(r >> 16);
}
static __device__ __forceinline__ float bf16_f32(unsigned short h) {
  return __builtin_bit_cast(float, (unsigned int)h << 16);
}
static __device__ __forceinline__ float exp2n(float x) {
  return __builtin_amdgcn_exp2f(x);    // native v_exp_f32
}

static __device__ __forceinline__ f32x4 mfma_bf16(short8 a, short8 b, f32x4 c) {
  return __builtin_amdgcn_mfma_f32_16x16x32_bf16(
      __builtin_bit_cast(bf16x8, a), __builtin_bit_cast(bf16x8, b), c, 0, 0, 0);
}
static __device__ __forceinline__ f32x16 mfma32(short8 a, short8 b, f32x16 c) {
  return __builtin_amdgcn_mfma_f32_32x32x16_bf16(
      __builtin_bit_cast(bf16x8, a), __builtin_bit_cast(bf16x8, b), c, 0, 0, 0);
}

// D = [bf16(S0) | bf16(S1)<<16]
static __device__ __forceinline__ unsigned int cvt_pk(float lo, float hi) {
  unsigned int r;
  asm("v_cvt_pk_bf16_f32 %0, %1, %2" : "=v"(r) : "v"(lo), "v"(hi));
  return r;
}
// v_permlane32_swap_b32 vdst, vsrc: a.hi32lanes <-> b.lo32lanes
static __device__ __forceinline__ void permswap(unsigned int& a, unsigned int& b) {
  asm("v_permlane32_swap_b32 %0, %1" : "+v"(a), "+v"(b));
}

static __device__ __forceinline__ int swz128(int a) {
  return a ^ (((a >> 7) & 7) << 4);
}
// K-bounce tile (row stride 256B): fold row bits 0-3 into byte bits 4-7
static __device__ __forceinline__ int swzK(int a) {
  return a ^ (((a >> 8) & 15) << 4);
}

// Fragment-major global layouts (written by proj, read coalesced by attn):
//  K: kfb[b][kblk(128)][f(8)][lane(64)] x 16B  — lane=h*32+l31 holds
//     K[kblk*32 + l31][f*16 + h*8 .. +8]           (8KB per kblk)
//  V: vfb[b][kblk(128)][dblk(4)][kk(2)][lane(64)] x 16B — lane holds
//     V[kblk*32 + kk*16 + h*8 .. +8][dblk*32 + l31] (8KB per kblk)

// ---------------- projection via MFMA, split-precision --------------------
__global__ __launch_bounds__(256) void proj_kernel(
    const float* __restrict__ x, const float* __restrict__ cond,
    const float* __restrict__ Wq, const float* __restrict__ bq,
    const float* __restrict__ Wk, const float* __restrict__ bk,
    const float* __restrict__ Wv, const float* __restrict__ bv,
    unsigned short* __restrict__ qb, unsigned short* __restrict__ kb,
    unsigned short* __restrict__ vt)
{
  const int which = blockIdx.y;
  const float* __restrict__ src  = (which == 0) ? x  : cond;
  const float* __restrict__ W    = (which == 0) ? Wq : (which == 1 ? Wk : Wv);
  const float* __restrict__ bias = (which == 0) ? bq : (which == 1 ? bk : bv);
  const int r0 = blockIdx.x * 64;

  __shared__ __align__(16) char lds[32768];
  char* const AhB = lds;
  char* const AlB = lds + 8192;
  char* const WtB = lds + 16384;

  const int tid  = threadIdx.x;
  const int wv   = tid >> 6;
  const int lane = tid & 63;
  const int g    = lane >> 4;
  const int c    = lane & 15;

  f32x4 acc[8];
  #pragma unroll
  for (int cf = 0; cf < 8; ++cf) acc[cf] = (f32x4){0.f, 0.f, 0.f, 0.f};

  for (int kt = 0; kt < 4; ++kt) {
    #pragma unroll
    for (int i = 0; i < 4; ++i) {
      const int idx = tid + i * 256;
      const int row = idx >> 4, f4 = idx & 15;
      const float4 a4 =
          *(const float4*)(src + (size_t)(r0 + row) * DIN + kt * 64 + f4 * 4);
      us4 hi, lo;
      const float av[4] = {a4.x, a4.y, a4.z, a4.w};
      #pragma unroll
      for (int e = 0; e < 4; ++e) {
        hi[e] = bf16_rn(av[e]);
        lo[e] = bf16_rn(av[e] - bf16_f32(hi[e]));
      }
      const int off = swz128(row * 128 + f4 * 8);
      *(us4*)(AhB + off) = hi;
      *(us4*)(AlB + off) = lo;
    }
    {
      const int col = tid & 127, half = tid >> 7;
      #pragma unroll
      for (int j = 0; j < 4; ++j) {
        const int k0 = half * 32 + j * 8;
        ushort8 wb;
        #pragma unroll
        for (int e = 0; e < 8; ++e)
          wb[e] = bf16_rn(W[(size_t)(kt * 64 + k0 + e) * DOUT + col]);
        *(ushort8*)(WtB + swz128(col * 128 + k0 * 2)) = wb;
      }
    }
    __syncthreads();

    #pragma unroll
    for (int ks = 0; ks < 2; ++ks) {
      const int aoff = (wv * 16 + c) * 128 + ks * 64 + g * 16;
      const short8 ah = *(const short8*)(AhB + swz128(aoff));
      const short8 al = *(const short8*)(AlB + swz128(aoff));
      #pragma unroll
      for (int cf = 0; cf < 8; ++cf) {
        const short8 wb =
            *(const short8*)(WtB + swz128((cf * 16 + c) * 128 + ks * 64 + g * 16));
        acc[cf] = mfma_bf16(ah, wb, acc[cf]);
        acc[cf] = mfma_bf16(al, wb, acc[cf]);
      }
    }
    __syncthreads();
  }

  if (which == 0) {
    // q scaled by log2(e) in f32 BEFORE the bf16 round (exp2-domain softmax)
    #pragma unroll
    for (int cf = 0; cf < 8; ++cf) {
      const float bb = bias[cf * 16 + c];
      #pragma unroll
      for (int r = 0; r < 4; ++r)
        qb[(size_t)(r0 + wv * 16 + g * 4 + r) * DOUT + cf * 16 + c] =
            bf16_rn((acc[cf][r] + bb) * LOG2E);
    }
  } else if (which == 1) {
    // K: bounce through swizzled LDS tile, then coalesced fragment-major stores
    char* const Ktile = lds;   // 16KB
    #pragma unroll
    for (int cf = 0; cf < 8; ++cf) {
      const float bb = bias[cf * 16 + c];
      #pragma unroll
      for (int r = 0; r < 4; ++r) {
        const int row = wv * 16 + g * 4 + r;
        *(unsigned short*)(Ktile + swzK(row * 256 + (cf * 16 + c) * 2)) =
            bf16_rn(acc[cf][r] + bb);
      }
    }
    __syncthreads();
    const int b2     = r0 >> 12;
    const int kblkG0 = (r0 & 4095) >> 5;
    #pragma unroll
    for (int j = 0; j < 4; ++j) {
      const int i    = tid + j * 256;
      const int kblk = i >> 9;
      const int rem  = i & 511;
      const int f    = rem >> 6;
      const int ln   = rem & 63;
      const int row  = kblk * 32 + (ln & 31);
      const int colb = f * 32 + (ln >> 5) * 16;
      const ushort8 v = *(const ushort8*)(Ktile + swzK(row * 256 + colb));
      *(ushort8*)((char*)kb +
          (((size_t)(b2 * 128 + kblkG0 + kblk) * 8 + f) * 64 + ln) * 16) = v;
    }
  } else {
    // fragment-major V (4 consecutive keys -> one us4 store)
    const int keybase = r0 + wv * 16 + g * 4;
    const int b2   = keybase >> 12;
    const int kblk = (keybase & 4095) >> 5;
    const int kk   = (keybase >> 4) & 1;
    const int h    = (keybase >> 3) & 1;
    const int e0   = keybase & 7;
    #pragma unroll
    for (int cf = 0; cf < 8; ++cf) {
      const float bb = bias[cf * 16 + c];
      const int col  = cf * 16 + c;
      const int dblk = col >> 5, l31 = col & 31;
      us4 pk;
      #pragma unroll
      for (int r = 0; r < 4; ++r) pk[r] = bf16_rn(acc[cf][r] + bb);
      *(us4*)(vt + (((((size_t)b2 * 128 + kblk) * 4 + dblk) * 2 + kk) * 64 +
                    h * 32 + l31) * 8 + e0) = pk;
    }
  }
}

// ---------------- flash attention: register-resident, no LDS in loop ------
// Block: 256 thr = 4 waves = 4 kv-splits of one 32-query tile.
// Wave: 32 q x 1024 keys, KVBLK=32/iter (32 iters), 32x32x16 MFMA.
// Depth-2 K prefetch (static A/B buffers, 2x-unrolled loop); depth-1 V.
// Native-exp2 softmax; defer-max THR=11 (log2); split QK accumulator chains.
constexpr int NSPLIT = 4;
constexpr int QBLK   = 32;
constexpr int KVBLK  = 32;
constexpr int ITERS  = SEQLEN / NSPLIT / KVBLK;   // 32 (even)

__global__ __launch_bounds__(256, 2) void attn_kernel(
    const unsigned short* __restrict__ qb,
    const unsigned short* __restrict__ kb,
    const unsigned short* __restrict__ vt,
    float* __restrict__ out)
{
  __shared__ __align__(16) float cmb[2][32][132];   // 33.8KB combine buffer
  __shared__ float Ml[NSPLIT][32][2];               // 1KB

  // XCD swizzle (512 blocks = 8 XCD x 64): one batch per XCD-pair -> L2-fit
  const int bid = ((blockIdx.x & 7) << 6) | (blockIdx.x >> 3);
  const int qt  = bid & 127;
  const int b   = bid >> 7;
  const int tid = threadIdx.x;
  const int split = tid >> 6;
  const int lane  = tid & 63;
  const int ql = lane & 31;   // query column this lane owns
  const int h  = lane >> 5;   // half-wave

  const int q0 = qt * QBLK;

  // ---- Q B-fragments (once) ----
  short8 qf[8];
  {
    const char* qp = (const char*)(qb + (size_t)(b * SEQLEN + q0 + ql) * DOUT) + h * 16;
    #pragma unroll
    for (int f = 0; f < 8; ++f) qf[f] = *(const short8*)(qp + f * 32);
  }

  // ---- fragment-major streaming bases ----
  const int kblk0 = split * (SEQLEN / NSPLIT / 32);   // split*32
  const char* kfb = (const char*)kb + ((size_t)b * 128 + kblk0) * 8192 + lane * 16;
  const char* vfb = (const char*)vt + ((size_t)b * 128 + kblk0) * 8192 + lane * 16;

  f32x16 acc[4];
  #pragma unroll
  for (int d = 0; d < 4; ++d)
    #pragma unroll
    for (int r = 0; r < 16; ++r) acc[d][r] = 0.f;
  float mc = -1e30f, lc = 0.f;

  // preload: K tiles 0,1 (A,B); V tile 0
  short8 kfA[8], kfB[8], vf[4][2];
  #pragma unroll
  for (int f = 0; f < 8; ++f) kfA[f] = *(const short8*)(kfb + f * 1024);
  #pragma unroll
  for (int f = 0; f < 8; ++f) kfB[f] = *(const short8*)(kfb + 8192 + f * 1024);
  kfb += 16384;                                   // -> tile 2
  #pragma unroll
  for (int d = 0; d < 4; ++d)
    #pragma unroll
    for (int kk = 0; kk < 2; ++kk)
      vf[d][kk] = *(const short8*)(vfb + (d * 2 + kk) * 1024);

  auto body = [&](short8 (&kf)[8], int t) {
    // ---- S^T = K Q^T, two independent chains (4-deep each) ----
    f32x16 s0, s1;
    #pragma unroll
    for (int r = 0; r < 16; ++r) { s0[r] = 0.f; s1[r] = 0.f; }
    __builtin_amdgcn_s_setprio(1);
    #pragma unroll
    for (int f = 0; f < 4; ++f) s0 = mfma32(kf[f], qf[f], s0);
    #pragma unroll
    for (int f = 0; f < 4; ++f) s1 = mfma32(kf[f + 4], qf[f + 4], s1);
    __builtin_amdgcn_s_setprio(0);

    // prefetch K(t+2) into the buffer just consumed (depth-2)
    if (t + 2 < ITERS) {
      #pragma unroll
      for (int f = 0; f < 8; ++f) kf[f] = *(const short8*)(kfb + f * 1024);
      kfb += 8192;
    }

    float s[16];
    #pragma unroll
    for (int r = 0; r < 16; ++r) s[r] = s0[r] + s1[r];

    // ---- softmax, defer-max (THR=11 log2 units: P <= 2048) ----
    float m01 = fmaxf(fmaxf(s[0],  s[1]),  s[2]);
    float m02 = fmaxf(fmaxf(s[3],  s[4]),  s[5]);
    float m03 = fmaxf(fmaxf(s[6],  s[7]),  s[8]);
    float m04 = fmaxf(fmaxf(s[9],  s[10]), s[11]);
    float m05 = fmaxf(fmaxf(s[12], s[13]), s[14]);
    float m11 = fmaxf(fmaxf(m01, m02), m03);
    float m12 = fmaxf(fmaxf(m04, m05), s[15]);
    float tm  = fmaxf(m11, m12);
    if (!__all(tm <= mc + 11.f)) {
      float tr = fmaxf(tm, __shfl_xor(tm, 32));
      const float mnew  = fmaxf(mc, tr);
      const float sc    = exp2n(mc - mnew);
      mc = mnew;
      lc *= sc;
      #pragma unroll
      for (int d = 0; d < 4; ++d)
        #pragma unroll
        for (int r = 0; r < 16; ++r) acc[d][r] *= sc;
    }
    float p[16];
    #pragma unroll
    for (int r = 0; r < 16; ++r) p[r] = exp2n(s[r] - mc);   // native v_exp_f32
    // tree sum
    float a0 = (p[0]+p[1]) + (p[2]+p[3]);
    float a1 = (p[4]+p[5]) + (p[6]+p[7]);
    float a2 = (p[8]+p[9]) + (p[10]+p[11]);
    float a3 = (p[12]+p[13]) + (p[14]+p[15]);
    lc += (a0 + a1) + (a2 + a3);

    // ---- P -> B-fragments in-register (T12) ----
    short8 pfrag[2];
    #pragma unroll
    for (int kk = 0; kk < 2; ++kk) {
      unsigned int A  = cvt_pk(p[kk * 8 + 0], p[kk * 8 + 1]);
      unsigned int Bv = cvt_pk(p[kk * 8 + 2], p[kk * 8 + 3]);
      unsigned int C  = cvt_pk(p[kk * 8 + 4], p[kk * 8 + 5]);
      unsigned int Dv = cvt_pk(p[kk * 8 + 6], p[kk * 8 + 7]);
      permswap(A, C);
      permswap(Bv, Dv);
      const u32x4 w = {A, Bv, C, Dv};
      pfrag[kk] = __builtin_bit_cast(short8, w);
    }

    // ---- O^T += V^T P^T (4 independent 2-deep chains) ----
    __builtin_amdgcn_s_setprio(1);
    #pragma unroll
    for (int d = 0; d < 4; ++d)
      #pragma unroll
      for (int kk = 0; kk < 2; ++kk)
        acc[d] = mfma32(vf[d][kk], pfrag[kk], acc[d]);
    __builtin_amdgcn_s_setprio(0);

    // prefetch V(t+1)
    if (t + 1 < ITERS) {
      vfb += 8192;
      #pragma unroll
      for (int d = 0; d < 4; ++d)
        #pragma unroll
        for (int kk = 0; kk < 2; ++kk)
          vf[d][kk] = *(const short8*)(vfb + (d * 2 + kk) * 1024);
    }
  };

  for (int t = 0; t < ITERS; t += 2) {
    body(kfA, t);
    body(kfB, t + 1);
  }

  // ---- cross-split combine (exp2 domain) ----
  lc += __shfl_xor(lc, 32);
  if (lane < 32) { Ml[split][ql][0] = mc; Ml[split][ql][1] = lc; }
  __syncthreads();

  float mg = -1e30f, lsum = 0.f;
  #pragma unroll
  for (int s2 = 0; s2 < NSPLIT; ++s2) mg = fmaxf(mg, Ml[s2][ql][0]);
  #pragma unroll
  for (int s2 = 0; s2 < NSPLIT; ++s2)
    lsum += Ml[s2][ql][1] * exp2n(Ml[s2][ql][0] - mg);
  const float fac = exp2n(mc - mg);
  #pragma unroll
  for (int d = 0; d < 4; ++d)
    #pragma unroll
    for (int r = 0; r < 16; ++r) acc[d][r] *= fac;

  // tree: {1,3} write -> {0,2} add -> {2} writes -> {0} adds -> out
  if (split & 1) {
    float* reg = &cmb[split >> 1][0][0];
    #pragma unroll
    for (int d = 0; d < 4; ++d)
      #pragma unroll
      for (int rr = 0; rr < 4; ++rr) {
        const f32x4 v = {acc[d][rr*4+0], acc[d][rr*4+1], acc[d][rr*4+2], acc[d][rr*4+3]};
        *(f32x4*)(reg + ql * 132 + d * 32 + rr * 8 + h * 4) = v;
      }
  }
  __syncthreads();
  if (!(split & 1)) {
    const float* reg = &cmb[split >> 1][0][0];
    #pragma unroll
    for (int d = 0; d < 4; ++d)
      #pragma unroll
      for (int rr = 0; rr < 4; ++rr) {
        const f32x4 v = *(const f32x4*)(reg + ql * 132 + d * 32 + rr * 8 + h * 4);
        acc[d][rr*4+0] += v.x; acc[d][rr*4+1] += v.y;
        acc[d][rr*4+2] += v.z; acc[d][rr*4+3] += v.w;
      }
  }
  __syncthreads();
  if (split == 2) {
    float* reg = &cmb[0][0][0];
    #pragma unroll
    for (int d = 0; d < 4; ++d)
      #pragma unroll
      for (int rr = 0; rr < 4; ++rr) {
        const f32x4 v = {acc[d][rr*4+0], acc[d][rr*4+1], acc[d][rr*4+2], acc[d][rr*4+3]};
        *(f32x4*)(reg + ql * 132 + d * 32 + rr * 8 + h * 4) = v;
      }
  }
  __syncthreads();
  if (split == 0) {
    const float* reg = &cmb[0][0][0];
    const float inv = 1.f / lsum;
    float* const op = out + (size_t)(b * SEQLEN + q0 + ql) * DOUT;
    #pragma unroll
    for (int d = 0; d < 4; ++d)
      #pragma unroll
      for (int rr = 0; rr < 4; ++rr) {
        const f32x4 v = *(const f32x4*)(reg + ql * 132 + d * 32 + rr * 8 + h * 4);
        f32x4 o;
        o.x = (acc[d][rr*4+0] + v.x) * inv;
        o.y = (acc[d][rr*4+1] + v.y) * inv;
        o.z = (acc[d][rr*4+2] + v.z) * inv;
        o.w = (acc[d][rr*4+3] + v.w) * inv;
        *(f32x4*)(op + d * 32 + rr * 8 + h * 4) = o;
      }
  }
}

extern "C" void kernel_launch(void* const* d_in, const int* in_sizes, int n_in,
                              void* d_out, int out_size, void* d_ws, size_t ws_size,
                              hipStream_t stream) {
  const float* x    = (const float*)d_in[0];
  const float* cond = (const float*)d_in[1];
  const float* Wq   = (const float*)d_in[2];
  const float* bq   = (const float*)d_in[3];
  const float* Wk   = (const float*)d_in[4];
  const float* bk   = (const float*)d_in[5];
  const float* Wv   = (const float*)d_in[6];
  const float* bv   = (const float*)d_in[7];
  float* out = (float*)d_out;

  unsigned short* qb = (unsigned short*)d_ws;                 // 4MB row-major (log2e-scaled)
  unsigned short* kb = qb + (size_t)ROWS * DOUT;              // 4MB fragment-major
  unsigned short* vt = kb + (size_t)ROWS * DOUT;              // 4MB fragment-major

  proj_kernel<<<dim3(ROWS / 64, 3), 256, 0, stream>>>(
      x, cond, Wq, bq, Wk, bk, Wv, bv, qb, kb, vt);

  attn_kernel<<<dim3(BATCH * (SEQLEN / QBLK)), 256, 0, stream>>>(
      qb, kb, vt, out);
}